// Round 1
// baseline (692.670 us; speedup 1.0000x reference)
//
#include <hip/hip_runtime.h>
#include <hip/hip_bf16.h>
#include <math.h>

#define NH   8
#define NSEQ 4096
#define NB   2
#define HID  256
#define VD   32
#define RANK 409   // 0-indexed lower order statistic; pos = 0.1*(4096-1) = 409.5

// ---------------- block-wide helpers (256 threads = 4 waves) ----------------

__device__ __forceinline__ float block_sum_f(float x, int tid, volatile float* s4) {
#pragma unroll
  for (int d = 32; d; d >>= 1) x += __shfl_down(x, d, 64);
  __syncthreads();
  if ((tid & 63) == 0) s4[tid >> 6] = x;
  __syncthreads();
  return ((s4[0] + s4[1]) + s4[2]) + s4[3];
}

__device__ __forceinline__ float block_min_f(float x, int tid, volatile float* s4) {
#pragma unroll
  for (int d = 32; d; d >>= 1) x = fminf(x, __shfl_down(x, d, 64));
  __syncthreads();
  if ((tid & 63) == 0) s4[tid >> 6] = x;
  __syncthreads();
  return fminf(fminf(s4[0], s4[1]), fminf(s4[2], s4[3]));
}

__device__ __forceinline__ float block_max_f(float x, int tid, volatile float* s4) {
#pragma unroll
  for (int d = 32; d; d >>= 1) x = fmaxf(x, __shfl_down(x, d, 64));
  __syncthreads();
  if ((tid & 63) == 0) s4[tid >> 6] = x;
  __syncthreads();
  return fmaxf(fmaxf(s4[0], s4[1]), fmaxf(s4[2], s4[3]));
}

__device__ __forceinline__ int block_sum_i(int x, int tid, volatile int* s4) {
#pragma unroll
  for (int d = 32; d; d >>= 1) x += __shfl_down(x, d, 64);
  __syncthreads();
  if ((tid & 63) == 0) s4[tid >> 6] = x;
  __syncthreads();
  return ((s4[0] + s4[1]) + s4[2]) + s4[3];
}

// exclusive scan over the 256 per-thread counts; also returns block total
__device__ __forceinline__ unsigned block_scan_excl(unsigned c, int tid,
                                                    volatile unsigned* s4,
                                                    unsigned& total) {
  const int lane = tid & 63, w = tid >> 6;
  unsigned incl = c;
#pragma unroll
  for (int d = 1; d < 64; d <<= 1) {
    unsigned o = __shfl_up(incl, d, 64);
    if (lane >= d) incl += o;
  }
  __syncthreads();
  if (lane == 63) s4[w] = incl;
  __syncthreads();
  unsigned base = 0;
#pragma unroll
  for (int i = 0; i < 4; i++)
    if (i < w) base += s4[i];
  total = s4[0] + s4[1] + s4[2] + s4[3];
  return base + incl - c;
}

// ---------------- kernel A: value[h][n][b*32+k] = x @ weight; + scales ------

__global__ __launch_bounds__(256) void value_kernel(
    const float* __restrict__ x, const float* __restrict__ w,
    const float* __restrict__ r, float* __restrict__ value,
    float* __restrict__ scales) {
  const int tid = threadIdx.x;

  if (blockIdx.x == 0 && tid < NH) {
    // replicate jax f32 semantics: c = f32(0.25*pi*(1-1e-7)); t = c*(1+sin(r)) in f32
    double rv = (double)r[tid];
    const float c0 = (float)(0.25 * 3.141592653589793 * (1.0 - 1e-07));
    float s1 = (float)sin(rv);
    float t = c0 * (1.0f + s1);
    scales[tid] = (float)tan((double)t);
  }

  const int n0 = blockIdx.x * 8;
  __shared__ float sx[NB][8][HID];
#pragma unroll
  for (int i = 0; i < 16; i++) {
    int idx = i * 256 + tid;          // 0..4095 over [b][nn][j]
    int b = idx >> 11;
    int rem = idx & 2047;
    int nn = rem >> 8;
    int j = rem & 255;
    sx[b][nn][j] = x[((size_t)b * NSEQ + n0 + nn) * HID + j];
  }
  __syncthreads();

  const int h = tid >> 5, k = tid & 31;
  float acc[NB][8];
#pragma unroll
  for (int b = 0; b < NB; b++)
#pragma unroll
    for (int nn = 0; nn < 8; nn++) acc[b][nn] = 0.f;

  const float* wp = w + (size_t)h * HID * VD + k;
  for (int j4 = 0; j4 < HID; j4 += 4) {
    float wv0 = wp[(size_t)(j4 + 0) * VD];
    float wv1 = wp[(size_t)(j4 + 1) * VD];
    float wv2 = wp[(size_t)(j4 + 2) * VD];
    float wv3 = wp[(size_t)(j4 + 3) * VD];
#pragma unroll
    for (int b = 0; b < NB; b++) {
#pragma unroll
      for (int nn = 0; nn < 8; nn++) {
        const float4 xv = *reinterpret_cast<const float4*>(&sx[b][nn][j4]);
        float a = acc[b][nn];
        a = fmaf(xv.x, wv0, a);
        a = fmaf(xv.y, wv1, a);
        a = fmaf(xv.z, wv2, a);
        a = fmaf(xv.w, wv3, a);
        acc[b][nn] = a;
      }
    }
  }
#pragma unroll
  for (int b = 0; b < NB; b++)
#pragma unroll
    for (int nn = 0; nn < 8; nn++)
      value[((size_t)h * NSEQ + n0 + nn) * (NB * VD) + b * VD + k] = acc[b][nn];
}

// ---------------- kernel B: per (h,q) row: percentile -> softmax -> gather --

__global__ __launch_bounds__(256) void attn_kernel(
    const float* __restrict__ m_dist, const float* __restrict__ value,
    const float* __restrict__ scales, float* __restrict__ out) {
  const int tid = threadIdx.x;
  const int lane = tid & 63;
  const int wv = tid >> 6;
  const int bid = blockIdx.x;
  const int h = bid >> 12;
  const int q = bid & (NSEQ - 1);

  __shared__ unsigned s_hist[1024];
  __shared__ float s_w[NSEQ];            // candidates, then weights
  __shared__ unsigned short s_idx[NSEQ];
  __shared__ float s_red[4];
  __shared__ int s_redi[4];
  __shared__ unsigned s_scan[4];
  __shared__ float s_out[4][64];
  __shared__ float s_bcf[2];
  __shared__ unsigned s_bcu[4];

  const float scale = scales[h];
  const size_t rowbase = ((size_t)(h * NSEQ + q)) * NSEQ;

  // ---- load row into registers: thread owns n = 16*tid + i (contiguous) ----
  float v[16];
  {
    const float4* row4 = reinterpret_cast<const float4*>(m_dist + rowbase) + (size_t)tid * 4;
#pragma unroll
    for (int a = 0; a < 4; a++) {
      float4 t4 = row4[a];
      v[4 * a + 0] = t4.x * scale;
      v[4 * a + 1] = t4.y * scale;
      v[4 * a + 2] = t4.z * scale;
      v[4 * a + 3] = t4.w * scale;
    }
  }
#pragma unroll
  for (int i = 0; i < 4; i++) s_hist[tid + 256 * i] = 0u;

  float lmin = v[0];
#pragma unroll
  for (int i = 1; i < 16; i++) lmin = fminf(lmin, v[i]);
  __syncthreads();

  // ---- level-1 linear histogram (monotone binning => value-partition) ----
  const float binscale = 1024.0f / scale;  // may be inf; NaN/inf conversions clamp
#pragma unroll
  for (int i = 0; i < 16; i++) {
    int bin = (int)(v[i] * binscale);
    bin = bin < 0 ? 0 : (bin > 1023 ? 1023 : bin);
    atomicAdd(&s_hist[bin], 1u);
  }
  __syncthreads();

  // locate bin containing rank RANK
  unsigned c4 = s_hist[4 * tid] + s_hist[4 * tid + 1] + s_hist[4 * tid + 2] + s_hist[4 * tid + 3];
  unsigned tot_unused;
  unsigned base = block_scan_excl(c4, tid, s_scan, tot_unused);
  if (base <= (unsigned)RANK && (unsigned)RANK < base + c4) {
    unsigned cum = base;
#pragma unroll
    for (int jj = 0; jj < 4; jj++) {
      unsigned hb = s_hist[4 * tid + jj];
      if ((unsigned)RANK < cum + hb) {
        s_bcu[0] = (unsigned)(4 * tid + jj);
        s_bcu[1] = (unsigned)RANK - cum;
        break;
      }
      cum += hb;
    }
  }
  if (tid == 0) s_bcu[2] = 0u;
  __syncthreads();
  const unsigned tbin = s_bcu[0];
  const unsigned r1 = s_bcu[1];

  // ---- compact candidates of tbin (order-invariant selection follows) ----
#pragma unroll
  for (int i = 0; i < 16; i++) {
    int bin = (int)(v[i] * binscale);
    bin = bin < 0 ? 0 : (bin > 1023 ? 1023 : bin);
    if ((unsigned)bin == tbin) {
      unsigned p = atomicAdd(&s_bcu[2], 1u);
      s_w[p] = v[i];
    }
  }
  __syncthreads();
  const unsigned c = s_bcu[2];

  float cmin = INFINITY, cmax = -INFINITY;
  for (unsigned j = tid; j < c; j += 256) {
    float u = s_w[j];
    cmin = fminf(cmin, u);
    cmax = fmaxf(cmax, u);
  }
  cmin = block_min_f(cmin, tid, s_red);
  cmax = block_max_f(cmax, tid, s_red);

  float v409;
  if (cmin == cmax) {  // uniform decision (block-reduced values)
    v409 = cmin;
  } else {
    if (tid == 0) s_bcf[0] = cmin;
    __syncthreads();
    for (unsigned j = tid; j < c; j += 256) {
      float u = s_w[j];
      int less = 0, eq = 0;
      for (unsigned kk = 0; kk < c; kk++) {
        float g = s_w[kk];
        less += (g < u);
        eq += (g == u);
      }
      if ((unsigned)less <= r1 && r1 < (unsigned)(less + eq)) s_bcf[0] = u;  // winners write same value
    }
    __syncthreads();
    v409 = s_bcf[0];
  }

  // ---- s[410] via cnt_le / min-greater; global min for softmax shift ----
  int cle = 0;
  float mgt = INFINITY;
#pragma unroll
  for (int i = 0; i < 16; i++) {
    cle += (v[i] <= v409) ? 1 : 0;
    if (v[i] > v409) mgt = fminf(mgt, v[i]);
  }
  int cleT = block_sum_i(cle, tid, s_redi);
  float mgtT = block_min_f(mgt, tid, s_red);
  float minT = block_min_f(lmin, tid, s_red);
  float v410 = (cleT >= RANK + 2) ? v409 : mgtT;
  float thr = 0.5f * v409 + 0.5f * v410;  // frac = 0.5 exactly (jax lerp)

  // ---- select <= thr, softmax weights, deterministic n-ordered compaction ----
  unsigned cnt = 0;
#pragma unroll
  for (int i = 0; i < 16; i++) cnt += (v[i] <= thr) ? 1u : 0u;
  unsigned M;
  unsigned pos = block_scan_excl(cnt, tid, s_scan, M);
  float psum = 0.f;
#pragma unroll
  for (int i = 0; i < 16; i++) {
    if (v[i] <= thr) {
      float p = expf(minT - v[i]);  // == exp(z - max(z)) of reference
      s_w[pos] = p;
      s_idx[pos] = (unsigned short)(16 * tid + i);
      pos++;
      psum += p;
    }
  }
  float denom = block_sum_f(psum, tid, s_red);
  float invd = 1.0f / denom;
  __syncthreads();

  // ---- gather: wave wv handles entries wv, wv+4, ...; lane = b*32+k --------
  const float* vp = value + (size_t)h * NSEQ * (NB * VD);
  float acc = 0.f;
  for (unsigned j = wv; j < M; j += 4) {
    float wgt = s_w[j];
    int n = (int)s_idx[j];
    acc = fmaf(wgt, vp[(size_t)n * (NB * VD) + lane], acc);
  }
  s_out[wv][lane] = acc;
  __syncthreads();

  if (tid < 64) {
    float totv = ((s_out[0][tid] + s_out[1][tid]) + s_out[2][tid]) + s_out[3][tid];
    float xo = totv * invd;
    // jax.nn.gelu approximate=True (tanh form)
    float x3 = xo * xo * xo;
    float inner = 0.7978845608028654f * (xo + 0.044715f * x3);
    float g = 0.5f * xo * (1.0f + tanhf(inner));
    int bb = tid >> 5, kk = tid & 31;
    out[((size_t)bb * NSEQ + q) * (NH * VD) + (size_t)h * VD + kk] = g;
  }
}

// ---------------- launch ----------------------------------------------------

extern "C" void kernel_launch(void* const* d_in, const int* in_sizes, int n_in,
                              void* d_out, int out_size, void* d_ws, size_t ws_size,
                              hipStream_t stream) {
  const float* m_dist = (const float*)d_in[0];
  const float* x = (const float*)d_in[1];
  const float* r = (const float*)d_in[2];
  const float* w = (const float*)d_in[3];
  float* out = (float*)d_out;

  float* value = (float*)d_ws;                          // NH*NSEQ*NB*VD floats = 8 MB
  float* scales = value + (size_t)NH * NSEQ * NB * VD;  // + 8 floats

  value_kernel<<<dim3(NSEQ / 8), dim3(256), 0, stream>>>(x, w, r, value, scales);
  attn_kernel<<<dim3(NH * NSEQ), dim3(256), 0, stream>>>(m_dist, value, scales, out);
}